// Round 1
// baseline (406.287 us; speedup 1.0000x reference)
//
#include <hip/hip_runtime.h>

// residualBlock: two sparse 3x3x3 convs (gather-GEMM over 27 offsets) with
// ReLU between and residual add. bf16 MFMA path (harness applies bf16 floor
// threshold ~0.112).
//
// ws layout (needs ~67.6 MB):
//   [0)                xb : bf16 x, (N+1) rows x 64  (row N = zeros, sentinel)
//   [33554560)         yb : bf16 relu(conv1), (N+1) rows x 64 (row N = zeros)
//   [67109120)         Wta: bf16 Wa transposed [k][j][i], 27*64*64
//   [67330304)         Wtb: bf16 Wb transposed [k][j][i], 27*64*64

#define N_ROWS 262144
#define HCH    64
#define KOFF   27

typedef unsigned short u16;
typedef __attribute__((ext_vector_type(8))) short short8;   // 8 bf16 (4 VGPRs)
typedef __attribute__((ext_vector_type(4))) float f32x4;    // 4 fp32 acc

__device__ __forceinline__ u16 f2bf(float f) {
    unsigned u = __builtin_bit_cast(unsigned, f);
    unsigned r = (u + 0x7FFFu + ((u >> 16) & 1u)) >> 16;   // RNE
    return (u16)r;
}

// ---------------------------------------------------------------- prep_x ----
// Convert x fp32 -> bf16 rows 0..N-1; zero row N of xb AND yb.
__global__ void prep_x(const float* __restrict__ x, u16* __restrict__ xb,
                       u16* __restrict__ yb) {
    long gid = (long)blockIdx.x * 256 + threadIdx.x;        // 8-elem chunks
    const long total = (long)N_ROWS * HCH / 8;              // 2,097,152
    if (gid < total) {
        const float4* s = (const float4*)(x + gid * 8);
        float4 a = s[0], b = s[1];
        unsigned p0 = f2bf(a.x) | ((unsigned)f2bf(a.y) << 16);
        unsigned p1 = f2bf(a.z) | ((unsigned)f2bf(a.w) << 16);
        unsigned p2 = f2bf(b.x) | ((unsigned)f2bf(b.y) << 16);
        unsigned p3 = f2bf(b.z) | ((unsigned)f2bf(b.w) << 16);
        uint4 v; v.x = p0; v.y = p1; v.z = p2; v.w = p3;
        *(uint4*)(xb + gid * 8) = v;
    } else if (gid < total + HCH / 8) {                     // zero row N
        long c = gid - total;
        uint4 z; z.x = 0; z.y = 0; z.z = 0; z.w = 0;
        *(uint4*)(xb + (long)N_ROWS * HCH + c * 8) = z;
        *(uint4*)(yb + (long)N_ROWS * HCH + c * 8) = z;
    }
}

// ---------------------------------------------------------------- prep_w ----
// W [k][i][j] fp32 -> Wt [k][j][i] bf16 (B^T layout: contiguous along GEMM-K)
__global__ void prep_w(const float* __restrict__ Wa, const float* __restrict__ Wb,
                       u16* __restrict__ Wta, u16* __restrict__ Wtb) {
    int gid = blockIdx.x * 256 + threadIdx.x;
    const int total = KOFF * HCH * HCH;                     // 110592
    const float* src; u16* dst; int e;
    if (gid < total)            { src = Wa; dst = Wta; e = gid; }
    else if (gid < 2 * total)   { src = Wb; dst = Wtb; e = gid - total; }
    else return;
    int k = e >> 12;            // /4096
    int i = (e >> 6) & 63;
    int j = e & 63;
    dst[(k << 12) + (j << 6) + i] = f2bf(src[e]);
}

// ------------------------------------------------------------------ conv ----
// Each block: 256 threads = 4 waves; each wave owns 4 row-tiles of 16 rows
// (block covers 256 rows). Loop k: stage Wt[k] (8KB bf16) into padded LDS,
// load 8 B-frags once per wave, reuse across 4 row-tiles (32 MFMAs per k).
// A-frags gathered directly from global bf16 rows (sentinel -> hot zero row).
template <bool FIRST>
__global__ __launch_bounds__(256) void conv_kernel(
    const u16* __restrict__ xg,      // gathered-from features, (N+1) x 64 bf16
    const u16* __restrict__ Wt,      // [27][64][64] bf16, [k][j][i]
    const int* __restrict__ nbr,     // [N][27]
    u16* __restrict__ ybf,           // FIRST: relu output bf16
    float* __restrict__ outf,        // !FIRST: final fp32 output
    const float* __restrict__ resid) // !FIRST: residual x fp32
{
    __shared__ u16 Wlds[64 * 72];    // padded stride 72 shorts (144B): no conflicts

    const int tid  = threadIdx.x;
    const int wave = tid >> 6;
    const int lane = tid & 63;
    const int m    = lane & 15;      // A row / B col / C col
    const int q    = lane >> 4;      // k-subgroup
    const int waveRowBase = blockIdx.x * 256 + wave * 64;

    f32x4 acc[4][4];                 // [row-tile][j-tile]
#pragma unroll
    for (int t = 0; t < 4; t++)
#pragma unroll
        for (int jt = 0; jt < 4; jt++)
            acc[t][jt] = (f32x4){0.f, 0.f, 0.f, 0.f};

    for (int k = 0; k < KOFF; k++) {
        __syncthreads();
        // stage Wt[k]: 64 rows x 128B -> LDS rows of 144B
        const uint4* wg = (const uint4*)(Wt + (k << 12));   // 512 x 16B
#pragma unroll
        for (int idx = tid; idx < 512; idx += 256) {
            int row = idx >> 3, ch = idx & 7;
            *(uint4*)&Wlds[row * 72 + ch * 8] = wg[idx];
        }
        __syncthreads();

        // B-frags: lane holds Wt[k][jt*16+m][h*32 + q*8 .. +7]
        short8 B[2][4];
#pragma unroll
        for (int jt = 0; jt < 4; jt++) {
            const u16* brow = &Wlds[(jt * 16 + m) * 72 + q * 8];
            B[0][jt] = *(const short8*)(brow);
            B[1][jt] = *(const short8*)(brow + 32);
        }

#pragma unroll
        for (int t = 0; t < 4; t++) {
            int row = waveRowBase + t * 16 + m;
            int r   = nbr[row * KOFF + k];                  // N => zero row
            const u16* arow = xg + (size_t)r * HCH + q * 8;
            short8 A0 = *(const short8*)(arow);
            short8 A1 = *(const short8*)(arow + 32);
#pragma unroll
            for (int jt = 0; jt < 4; jt++) {
                acc[t][jt] = __builtin_amdgcn_mfma_f32_16x16x32_bf16(
                    A0, B[0][jt], acc[t][jt], 0, 0, 0);
                acc[t][jt] = __builtin_amdgcn_mfma_f32_16x16x32_bf16(
                    A1, B[1][jt], acc[t][jt], 0, 0, 0);
            }
        }
    }

    // epilogue: C/D layout col = lane&15, row = q*4 + reg
#pragma unroll
    for (int t = 0; t < 4; t++) {
        int rowb = waveRowBase + t * 16 + q * 4;
#pragma unroll
        for (int jt = 0; jt < 4; jt++) {
            int col = jt * 16 + m;
#pragma unroll
            for (int rr = 0; rr < 4; rr++) {
                float v = acc[t][jt][rr];
                size_t off = (size_t)(rowb + rr) * HCH + col;
                if (FIRST) {
                    v = fmaxf(v, 0.f);
                    ybf[off] = f2bf(v);
                } else {
                    outf[off] = v + resid[off];
                }
            }
        }
    }
}

// ---------------------------------------------------------------- launch ----
extern "C" void kernel_launch(void* const* d_in, const int* in_sizes, int n_in,
                              void* d_out, int out_size, void* d_ws, size_t ws_size,
                              hipStream_t stream) {
    const float* x   = (const float*)d_in[0];
    const float* Wa  = (const float*)d_in[1];
    const float* Wb  = (const float*)d_in[2];
    const int*   nbr = (const int*)d_in[3];
    float* out = (float*)d_out;

    char* ws = (char*)d_ws;
    const size_t xb_bytes = (size_t)(N_ROWS + 1) * HCH * sizeof(u16); // 33,554,560
    u16* xb  = (u16*)ws;
    u16* yb  = (u16*)(ws + xb_bytes);
    u16* Wta = (u16*)(ws + 2 * xb_bytes);
    u16* Wtb = Wta + KOFF * HCH * HCH;

    prep_x<<<8193, 256, 0, stream>>>(x, xb, yb);
    prep_w<<<864, 256, 0, stream>>>(Wa, Wb, Wta, Wtb);
    conv_kernel<true ><<<N_ROWS / 256, 256, 0, stream>>>(xb, Wta, nbr, yb, nullptr, nullptr);
    conv_kernel<false><<<N_ROWS / 256, 256, 0, stream>>>(yb, Wtb, nbr, nullptr, out, x);
}